// Round 2
// baseline (1383.157 us; speedup 1.0000x reference)
//
#include <hip/hip_runtime.h>
#include <hip/hip_bf16.h>

typedef unsigned int uint;
typedef unsigned short ushort;

// ---- bf16 helpers (f32 accumulate everywhere; bf16 only for stored node state h=[x|s]) ----
__device__ __forceinline__ float2 bf2f2(uint p) {
    float2 r;
    r.x = __uint_as_float(p << 16);
    r.y = __uint_as_float(p & 0xffff0000u);
    return r;
}
__device__ __forceinline__ ushort f2bf(float f) {
    uint u = __float_as_uint(f);
    uint r = (u + 0x7fffu + ((u >> 16) & 1u)) >> 16;
    return (ushort)r;
}

// ---------------- CSR build ----------------
__global__ void k_hist(const int* __restrict__ dst, int* __restrict__ cnt, int E) {
    int e = blockIdx.x * 256 + threadIdx.x;
    if (e < E) atomicAdd(&cnt[dst[e]], 1);
}

__device__ __forceinline__ int block_excl_scan(int tsum, int tid, int* wtot) {
    int lane = tid & 63, w = tid >> 6;
    int incl = tsum;
    for (int off = 1; off < 64; off <<= 1) {
        int t = __shfl_up(incl, off);
        if (lane >= off) incl += t;
    }
    if (lane == 63) wtot[w] = incl;
    __syncthreads();
    int woff = 0;
    if (w > 0) woff = wtot[0];
    if (w > 1) woff += wtot[1];
    if (w > 2) woff += wtot[2];
    return woff + incl - tsum;
}

// per-block (1024-elem chunk) totals
__global__ __launch_bounds__(256)
void k_scanA(const int* __restrict__ cnt, int* __restrict__ btot, int N) {
    __shared__ int wtot[4];
    int tid = threadIdx.x;
    int base = blockIdx.x * 1024 + tid * 4;
    int s = 0;
    if (base + 3 < N) {
        int4 v = *reinterpret_cast<const int4*>(&cnt[base]);
        s = v.x + v.y + v.z + v.w;
    } else {
#pragma unroll
        for (int q = 0; q < 4; ++q) { int i = base + q; if (i < N) s += cnt[i]; }
    }
    int lane = tid & 63, w = tid >> 6;
    for (int off = 32; off; off >>= 1) s += __shfl_down(s, off);
    if (lane == 0) wtot[w] = s;
    __syncthreads();
    if (tid == 0) btot[blockIdx.x] = wtot[0] + wtot[1] + wtot[2] + wtot[3];
}

// scan the (<=256) block totals
__global__ __launch_bounds__(256)
void k_scanB(const int* __restrict__ btot, int* __restrict__ boff,
             int* __restrict__ rowptr, int NB, int N, int E) {
    __shared__ int wtot[4];
    int tid = threadIdx.x;
    int v = (tid < NB) ? btot[tid] : 0;
    int ex = block_excl_scan(v, tid, wtot);
    if (tid < NB) boff[tid] = ex;
    if (tid == 0) rowptr[N] = E;
}

// re-scan chunks, add block offset, write rowptr + cursor
__global__ __launch_bounds__(256)
void k_scanC(int* __restrict__ cnt, const int* __restrict__ boff,
             int* __restrict__ rowptr, int N) {
    __shared__ int wtot[4];
    int tid = threadIdx.x;
    int base = blockIdx.x * 1024 + tid * 4;
    int v0 = 0, v1 = 0, v2 = 0, v3 = 0;
    if (base + 3 < N) {
        int4 v = *reinterpret_cast<const int4*>(&cnt[base]);
        v0 = v.x; v1 = v.y; v2 = v.z; v3 = v.w;
    } else {
        if (base + 0 < N) v0 = cnt[base + 0];
        if (base + 1 < N) v1 = cnt[base + 1];
        if (base + 2 < N) v2 = cnt[base + 2];
        if (base + 3 < N) v3 = cnt[base + 3];
    }
    int tsum = v0 + v1 + v2 + v3;
    int ex = block_excl_scan(tsum, tid, wtot) + boff[blockIdx.x];
    int r0 = ex, r1 = ex + v0, r2 = r1 + v1, r3 = r2 + v2;
    if (base + 0 < N) { rowptr[base + 0] = r0; cnt[base + 0] = r0; }
    if (base + 1 < N) { rowptr[base + 1] = r1; cnt[base + 1] = r1; }
    if (base + 2 < N) { rowptr[base + 2] = r2; cnt[base + 2] = r2; }
    if (base + 3 < N) { rowptr[base + 3] = r3; cnt[base + 3] = r3; }
}

__global__ void k_fill(const int* __restrict__ src, const int* __restrict__ dst,
                       int* __restrict__ cursor, int* __restrict__ col, int E) {
    int e = blockIdx.x * 256 + threadIdx.x;
    if (e < E) {
        int p = atomicAdd(&cursor[dst[e]], 1);
        col[p] = src[e];
    }
}

__global__ void k_dinv(const int* __restrict__ rowptr, float* __restrict__ dinv, int N) {
    int v = blockIdx.x * 256 + threadIdx.x;
    if (v < N) {
        float deg = (float)(rowptr[v + 1] - rowptr[v]) + 1.0f;  // + self loop
        dinv[v] = 1.0f / sqrtf(deg);
    }
}

// pack h0 = [x | s] as bf16, row stride 128
__global__ void k_pack(const float4* __restrict__ xi, const float4* __restrict__ si,
                       ushort* __restrict__ h, int n4) {   // n4 = N*16
    int i = blockIdx.x * 256 + threadIdx.x;
    if (i >= n4) return;
    int row = i >> 4, c4 = i & 15;
    float4 xv = xi[i], sv = si[i];
    ushort4 xo, so;
    xo.x = f2bf(xv.x); xo.y = f2bf(xv.y); xo.z = f2bf(xv.z); xo.w = f2bf(xv.w);
    so.x = f2bf(sv.x); so.y = f2bf(sv.y); so.z = f2bf(sv.z); so.w = f2bf(sv.w);
    *reinterpret_cast<ushort4*>(&h[(size_t)row * 128 + c4 * 4]) = xo;
    *reinterpret_cast<ushort4*>(&h[(size_t)row * 128 + 64 + c4 * 4]) = so;
}

// ---------------- fused gather: GIN agg of h AND dinv-weighted agg of s ----------------
// one wave per dst row; lane l holds features (2l, 2l+1) of the 128-wide h row
__global__ __launch_bounds__(256)
void k_agg(const uint* __restrict__ h32, const float* __restrict__ dinv,
           const int* __restrict__ rowptr, const int* __restrict__ col,
           float* __restrict__ g, float* __restrict__ tb, int N) {
    int w = threadIdx.x >> 6, l = threadIdx.x & 63;
    int v = blockIdx.x * 4 + w;
    if (v >= N) return;
    float dv = dinv[v];
    float2 hv = bf2f2(h32[(size_t)v * 64 + l]);
    float2 acc = hv;
    float2 accd = make_float2(dv * hv.x, dv * hv.y);
    int k = rowptr[v], end = rowptr[v + 1];
    for (; k + 1 < end; k += 2) {
        int u0 = col[k], u1 = col[k + 1];
        float d0 = dinv[u0], d1 = dinv[u1];
        float2 a = bf2f2(h32[(size_t)u0 * 64 + l]);
        float2 b = bf2f2(h32[(size_t)u1 * 64 + l]);
        acc.x += a.x + b.x;        acc.y += a.y + b.y;
        accd.x = fmaf(d0, a.x, fmaf(d1, b.x, accd.x));
        accd.y = fmaf(d0, a.y, fmaf(d1, b.y, accd.y));
    }
    if (k < end) {
        int u = col[k];
        float du = dinv[u];
        float2 a = bf2f2(h32[(size_t)u * 64 + l]);
        acc.x += a.x; acc.y += a.y;
        accd.x = fmaf(du, a.x, accd.x);
        accd.y = fmaf(du, a.y, accd.y);
    }
    *reinterpret_cast<float2*>(&g[(size_t)v * 128 + 2 * l]) = acc;
    if (l >= 32) {
        float2 tv = make_float2(dv * accd.x, dv * accd.y);
        *reinterpret_cast<float2*>(&tb[(size_t)v * 64 + (2 * l - 64)]) = tv;
    }
}

// ---------------- fused per-layer GEMMs: x' = leaky(g@W1)@W2 ; s' = tanh(t@Wg + bg) ----------------
__global__ __launch_bounds__(512)
void k_layer(const float* __restrict__ g, const float* __restrict__ tb,
             const float* __restrict__ W1, const float* __restrict__ W2,
             const float* __restrict__ Wg, const float* __restrict__ bg,
             ushort* __restrict__ hout, int N) {
    __shared__ float sW1[8192];
    __shared__ float sW2[4096];
    __shared__ float sWg[4096];
    __shared__ float sIn[16][128];
    __shared__ float sT[16][64];
    __shared__ float sTi[16][64];
    for (int i = threadIdx.x; i < 8192; i += 512) sW1[i] = W1[i];
    for (int i = threadIdx.x; i < 4096; i += 512) { sW2[i] = W2[i]; sWg[i] = Wg[i]; }
    int w = threadIdx.x >> 6, j = threadIdx.x & 63;
    int ra = 2 * w, rb = ra + 1;
    float bgj = bg[j];
    for (int r0 = blockIdx.x * 16; r0 < N; r0 += gridDim.x * 16) {
        __syncthreads();
        {
            int t = threadIdx.x;
            int rr = t >> 5, c = (t & 31) << 2;
            int r = r0 + rr;
            float4 v = make_float4(0.f, 0.f, 0.f, 0.f);
            if (r < N) v = *reinterpret_cast<const float4*>(&g[(size_t)r * 128 + c]);
            *reinterpret_cast<float4*>(&sIn[rr][c]) = v;
            if (t < 256) {
                int rr2 = t >> 4, c2 = (t & 15) << 2;
                int r2 = r0 + rr2;
                float4 v2 = make_float4(0.f, 0.f, 0.f, 0.f);
                if (r2 < N) v2 = *reinterpret_cast<const float4*>(&tb[(size_t)r2 * 64 + c2]);
                *reinterpret_cast<float4*>(&sTi[rr2][c2]) = v2;
            }
        }
        __syncthreads();
        // stage 1: leaky(g @ W1) -> sT
        float e0 = 0.f, o0 = 0.f, e1 = 0.f, o1 = 0.f;
#pragma unroll
        for (int k = 0; k < 128; k += 4) {
            float4 a = *reinterpret_cast<const float4*>(&sIn[ra][k]);
            float4 b = *reinterpret_cast<const float4*>(&sIn[rb][k]);
            float w0 = sW1[(k + 0) * 64 + j], w1 = sW1[(k + 1) * 64 + j];
            float w2 = sW1[(k + 2) * 64 + j], w3 = sW1[(k + 3) * 64 + j];
            e0 = fmaf(a.x, w0, fmaf(a.z, w2, e0)); o0 = fmaf(a.y, w1, fmaf(a.w, w3, o0));
            e1 = fmaf(b.x, w0, fmaf(b.z, w2, e1)); o1 = fmaf(b.y, w1, fmaf(b.w, w3, o1));
        }
        float t0 = e0 + o0, t1 = e1 + o1;
        t0 = t0 > 0.f ? t0 : 0.01f * t0;
        t1 = t1 > 0.f ? t1 : 0.01f * t1;
        sT[ra][j] = t0; sT[rb][j] = t1;
        __syncthreads();
        // stage 2: x' = sT @ W2 ; gcn: s' = tanh(sTi @ Wg + bg)
        float x0 = 0.f, x1 = 0.f, y0 = 0.f, y1 = 0.f;
        float g0 = 0.f, g1 = 0.f, q0 = 0.f, q1 = 0.f;
#pragma unroll
        for (int k = 0; k < 64; k += 4) {
            float4 a = *reinterpret_cast<const float4*>(&sT[ra][k]);
            float4 b = *reinterpret_cast<const float4*>(&sT[rb][k]);
            float4 c = *reinterpret_cast<const float4*>(&sTi[ra][k]);
            float4 d = *reinterpret_cast<const float4*>(&sTi[rb][k]);
            float w0 = sW2[(k + 0) * 64 + j], w1 = sW2[(k + 1) * 64 + j];
            float w2 = sW2[(k + 2) * 64 + j], w3 = sW2[(k + 3) * 64 + j];
            float u0 = sWg[(k + 0) * 64 + j], u1 = sWg[(k + 1) * 64 + j];
            float u2 = sWg[(k + 2) * 64 + j], u3 = sWg[(k + 3) * 64 + j];
            x0 = fmaf(a.x, w0, fmaf(a.z, w2, x0)); y0 = fmaf(a.y, w1, fmaf(a.w, w3, y0));
            x1 = fmaf(b.x, w0, fmaf(b.z, w2, x1)); y1 = fmaf(b.y, w1, fmaf(b.w, w3, y1));
            g0 = fmaf(c.x, u0, fmaf(c.z, u2, g0)); q0 = fmaf(c.y, u1, fmaf(c.w, u3, q0));
            g1 = fmaf(d.x, u0, fmaf(d.z, u2, g1)); q1 = fmaf(d.y, u1, fmaf(d.w, u3, q1));
        }
        float xa = x0 + y0, xb = x1 + y1;
        float sa = tanhf(g0 + q0 + bgj), sb = tanhf(g1 + q1 + bgj);
        int r_a = r0 + ra, r_b = r0 + rb;
        if (r_a < N) {
            hout[(size_t)r_a * 128 + j] = f2bf(xa);
            hout[(size_t)r_a * 128 + 64 + j] = f2bf(sa);
        }
        if (r_b < N) {
            hout[(size_t)r_b * 128 + j] = f2bf(xb);
            hout[(size_t)r_b * 128 + 64 + j] = f2bf(sb);
        }
    }
}

// ---------------- BatchNorm (final layer only) ----------------
__global__ __launch_bounds__(256)
void k_bnstats(const ushort* __restrict__ h, float* __restrict__ stats, int N) {
    __shared__ float ls[4][64], ls2[4][64];
    int w = threadIdx.x >> 6, j = threadIdx.x & 63;
    float s = 0.f, s2 = 0.f;
    for (int r = blockIdx.x * 4 + w; r < N; r += gridDim.x * 4) {
        float v = __uint_as_float((uint)h[(size_t)r * 128 + j] << 16);
        s += v; s2 += v * v;
    }
    ls[w][j] = s; ls2[w][j] = s2;
    __syncthreads();
    if (w == 0) {
        s = ls[0][j] + ls[1][j] + ls[2][j] + ls[3][j];
        s2 = ls2[0][j] + ls2[1][j] + ls2[2][j] + ls2[3][j];
        atomicAdd(&stats[j], s);
        atomicAdd(&stats[64 + j], s2);
    }
}

// normalize x-half of h in place (bf16) and write f32 x_local output
__global__ void k_bnapply(ushort* __restrict__ h, const float* __restrict__ stats,
                          const float* __restrict__ gamma, const float* __restrict__ beta,
                          float* __restrict__ xlocal, int N) {
    int i = blockIdx.x * 256 + threadIdx.x;
    if (i < N * 64) {
        int r = i >> 6, j = i & 63;
        float invN = 1.0f / (float)N;
        float mean = stats[j] * invN;
        float var = stats[64 + j] * invN - mean * mean;
        float inv = rsqrtf(var + 1e-4f);
        float v = __uint_as_float((uint)h[(size_t)r * 128 + j] << 16);
        float xn = gamma[j] * (v - mean) * inv + beta[j];
        xlocal[i] = xn;
        h[(size_t)r * 128 + j] = f2bf(xn);
    }
}

// ---------------- final GEMM: h(bf16, 128-wide) @ Wh + bh ----------------
__global__ __launch_bounds__(512)
void k_final(const uint* __restrict__ h32, const float* __restrict__ Wh,
             const float* __restrict__ bh, float* __restrict__ out, int N) {
    __shared__ float sW[8192];
    __shared__ float sIn[16][128];
    for (int i = threadIdx.x; i < 8192; i += 512) sW[i] = Wh[i];
    int w = threadIdx.x >> 6, j = threadIdx.x & 63;
    int ra = 2 * w, rb = ra + 1;
    float bias = bh[j];
    for (int r0 = blockIdx.x * 16; r0 < N; r0 += gridDim.x * 16) {
        __syncthreads();
        {
            int t = threadIdx.x;
            int e = t * 4;
            int rr = e >> 7, c = e & 127;
            int r = r0 + rr;
            if (r < N) {
                uint2 p = *reinterpret_cast<const uint2*>(&h32[(size_t)r * 64 + (c >> 1)]);
                float2 f0 = bf2f2(p.x), f1 = bf2f2(p.y);
                sIn[rr][c + 0] = f0.x; sIn[rr][c + 1] = f0.y;
                sIn[rr][c + 2] = f1.x; sIn[rr][c + 3] = f1.y;
            } else {
                sIn[rr][c + 0] = 0.f; sIn[rr][c + 1] = 0.f;
                sIn[rr][c + 2] = 0.f; sIn[rr][c + 3] = 0.f;
            }
        }
        __syncthreads();
        float e0 = 0.f, o0 = 0.f, e1 = 0.f, o1 = 0.f;
#pragma unroll
        for (int k = 0; k < 128; k += 4) {
            float4 a = *reinterpret_cast<const float4*>(&sIn[ra][k]);
            float4 b = *reinterpret_cast<const float4*>(&sIn[rb][k]);
            float w0 = sW[(k + 0) * 64 + j], w1 = sW[(k + 1) * 64 + j];
            float w2 = sW[(k + 2) * 64 + j], w3 = sW[(k + 3) * 64 + j];
            e0 = fmaf(a.x, w0, fmaf(a.z, w2, e0)); o0 = fmaf(a.y, w1, fmaf(a.w, w3, o0));
            e1 = fmaf(b.x, w0, fmaf(b.z, w2, e1)); o1 = fmaf(b.y, w1, fmaf(b.w, w3, o1));
        }
        int r_a = r0 + ra, r_b = r0 + rb;
        if (r_a < N) out[(size_t)r_a * 64 + j] = e0 + o0 + bias;
        if (r_b < N) out[(size_t)r_b * 64 + j] = e1 + o1 + bias;
    }
}

// ---------------- pooling: one block per graph (batch is sorted) ----------------
__global__ __launch_bounds__(256)
void k_pool(const float* __restrict__ out, const int* __restrict__ batch,
            float* __restrict__ pooled, int N) {
    int g = blockIdx.x;
    int lo, hi;
    { int a = 0, b = N; while (a < b) { int m = (a + b) >> 1; if (batch[m] < g) a = m + 1; else b = m; } lo = a; }
    { int a = lo, b = N; while (a < b) { int m = (a + b) >> 1; if (batch[m] < g + 1) a = m + 1; else b = m; } hi = a; }
    int w = threadIdx.x >> 6, j = threadIdx.x & 63;
    float s = 0.f;
    for (int r = lo + w; r < hi; r += 4) s += out[(size_t)r * 64 + j];
    __shared__ float ls[4][64];
    ls[w][j] = s;
    __syncthreads();
    if (w == 0) pooled[g * 64 + j] = ls[0][j] + ls[1][j] + ls[2][j] + ls[3][j];
}

extern "C" void kernel_launch(void* const* d_in, const int* in_sizes, int n_in,
                              void* d_out, int out_size, void* d_ws, size_t ws_size,
                              hipStream_t stream) {
    const float* x_in  = (const float*)d_in[0];
    const float* s_in  = (const float*)d_in[1];
    const float* W1    = (const float*)d_in[2];
    const float* W2    = (const float*)d_in[3];
    const float* gamma = (const float*)d_in[4];
    const float* beta  = (const float*)d_in[5];
    const float* Wg    = (const float*)d_in[6];
    const float* bg    = (const float*)d_in[7];
    const float* Wh    = (const float*)d_in[8];
    const float* bh    = (const float*)d_in[9];
    const int*   ei    = (const int*)d_in[10];
    const int*   batch = (const int*)d_in[11];

    int N = in_sizes[0] / 64;
    int E = in_sizes[10] / 2;
    int L = in_sizes[2] / 8192;
    int G = out_size / 64 - N;

    const int* src = ei;
    const int* dst = ei + E;

    float* pooled = (float*)d_out;
    float* xlocal = pooled + (size_t)G * 64;     // final BN'd x lands here
    float* tbuf   = xlocal;                      // t (GCN pre-GEMM agg) borrows this slot during layers

    char* p = (char*)d_ws;
    ushort* h16  = (ushort*)p;  p += (size_t)N * 128 * 2;
    float* g     = (float*)p;   p += (size_t)N * 128 * 4;   // agg output / final-out reuse
    float* dinv  = (float*)p;   p += (size_t)N * 4;
    float* stats = (float*)p;   p += 128 * 4;
    int* rowptr  = (int*)p;     p += (size_t)(N + 1) * 4;
    int* cnt     = (int*)p;     p += (size_t)N * 4;          // histogram, then fill cursor
    int* col     = (int*)p;     p += (size_t)E * 4;
    int* btot    = (int*)p;     p += 256 * 4;
    int* boff    = (int*)p;     p += 256 * 4;
    const uint* h32 = (const uint*)h16;

    int NB = (N + 1023) / 1024;

    hipMemsetAsync(cnt, 0, (size_t)N * sizeof(int), stream);
    k_hist<<<(E + 255) / 256, 256, 0, stream>>>(dst, cnt, E);
    k_scanA<<<NB, 256, 0, stream>>>(cnt, btot, N);
    k_scanB<<<1, 256, 0, stream>>>(btot, boff, rowptr, NB, N, E);
    k_scanC<<<NB, 256, 0, stream>>>(cnt, boff, rowptr, N);
    k_fill<<<(E + 255) / 256, 256, 0, stream>>>(src, dst, cnt, col, E);
    k_dinv<<<(N + 255) / 256, 256, 0, stream>>>(rowptr, dinv, N);
    k_pack<<<(N * 16 + 255) / 256, 256, 0, stream>>>((const float4*)x_in, (const float4*)s_in, h16, N * 16);

    for (int i = 0; i < L; ++i) {
        k_agg<<<(N + 3) / 4, 256, 0, stream>>>(h32, dinv, rowptr, col, g, tbuf, N);
        k_layer<<<512, 512, 0, stream>>>(g, tbuf,
                                         W1 + (size_t)i * 8192, W2 + (size_t)i * 4096,
                                         Wg + (size_t)i * 4096, bg + (size_t)i * 64,
                                         h16, N);
    }

    hipMemsetAsync(stats, 0, 128 * sizeof(float), stream);
    k_bnstats<<<256, 256, 0, stream>>>(h16, stats, N);
    k_bnapply<<<(N * 64 + 255) / 256, 256, 0, stream>>>(h16, stats,
                                                        gamma + (size_t)(L - 1) * 64,
                                                        beta + (size_t)(L - 1) * 64,
                                                        xlocal, N);
    k_final<<<512, 512, 0, stream>>>(h32, Wh, bh, g, N);
    k_pool<<<G, 256, 0, stream>>>(g, batch, pooled, N);
}

// Round 3
// 401.211 us; speedup vs baseline: 3.4475x; 3.4475x over previous
//
#include <hip/hip_runtime.h>
#include <hip/hip_bf16.h>

typedef unsigned int uint;
typedef unsigned short ushort;
typedef __attribute__((ext_vector_type(8))) short bf16x8;
typedef __attribute__((ext_vector_type(4))) float f32x4;

// ---- bf16 helpers (f32 accumulate everywhere; bf16 only for stored tensors) ----
__device__ __forceinline__ float2 bf2f2(uint p) {
    float2 r;
    r.x = __uint_as_float(p << 16);
    r.y = __uint_as_float(p & 0xffff0000u);
    return r;
}
__device__ __forceinline__ ushort f2bf(float f) {
    uint u = __float_as_uint(f);
    return (ushort)((u + 0x7fffu + ((u >> 16) & 1u)) >> 16);
}
__device__ __forceinline__ uint packbf(float a, float b) {
    return (uint)f2bf(a) | ((uint)f2bf(b) << 16);
}

// ---------------- CSR build ----------------
__global__ void k_hist(const int* __restrict__ dst, int* __restrict__ cnt, int E) {
    int e = blockIdx.x * 256 + threadIdx.x;
    if (e < E) atomicAdd(&cnt[dst[e]], 1);
}

__device__ __forceinline__ int block_excl_scan(int tsum, int tid, int* wtot) {
    int lane = tid & 63, w = tid >> 6;
    int incl = tsum;
    for (int off = 1; off < 64; off <<= 1) {
        int t = __shfl_up(incl, off);
        if (lane >= off) incl += t;
    }
    if (lane == 63) wtot[w] = incl;
    __syncthreads();
    int woff = 0;
    if (w > 0) woff = wtot[0];
    if (w > 1) woff += wtot[1];
    if (w > 2) woff += wtot[2];
    return woff + incl - tsum;
}

__global__ __launch_bounds__(256)
void k_scanA(const int* __restrict__ cnt, int* __restrict__ btot, int N) {
    __shared__ int wtot[4];
    int tid = threadIdx.x;
    int base = blockIdx.x * 1024 + tid * 4;
    int s = 0;
    if (base + 3 < N) {
        int4 v = *reinterpret_cast<const int4*>(&cnt[base]);
        s = v.x + v.y + v.z + v.w;
    } else {
#pragma unroll
        for (int q = 0; q < 4; ++q) { int i = base + q; if (i < N) s += cnt[i]; }
    }
    int lane = tid & 63, w = tid >> 6;
    for (int off = 32; off; off >>= 1) s += __shfl_down(s, off);
    if (lane == 0) wtot[w] = s;
    __syncthreads();
    if (tid == 0) btot[blockIdx.x] = wtot[0] + wtot[1] + wtot[2] + wtot[3];
}

__global__ __launch_bounds__(256)
void k_scanB(const int* __restrict__ btot, int* __restrict__ boff,
             int* __restrict__ rowptr, int NB, int N, int E) {
    __shared__ int wtot[4];
    int tid = threadIdx.x;
    int v = (tid < NB) ? btot[tid] : 0;
    int ex = block_excl_scan(v, tid, wtot);
    if (tid < NB) boff[tid] = ex;
    if (tid == 0) rowptr[N] = E;
}

__global__ __launch_bounds__(256)
void k_scanC(int* __restrict__ cnt, const int* __restrict__ boff,
             int* __restrict__ rowptr, int N) {
    __shared__ int wtot[4];
    int tid = threadIdx.x;
    int base = blockIdx.x * 1024 + tid * 4;
    int v0 = 0, v1 = 0, v2 = 0, v3 = 0;
    if (base + 3 < N) {
        int4 v = *reinterpret_cast<const int4*>(&cnt[base]);
        v0 = v.x; v1 = v.y; v2 = v.z; v3 = v.w;
    } else {
        if (base + 0 < N) v0 = cnt[base + 0];
        if (base + 1 < N) v1 = cnt[base + 1];
        if (base + 2 < N) v2 = cnt[base + 2];
        if (base + 3 < N) v3 = cnt[base + 3];
    }
    int tsum = v0 + v1 + v2 + v3;
    int ex = block_excl_scan(tsum, tid, wtot) + boff[blockIdx.x];
    int r0 = ex, r1 = ex + v0, r2 = r1 + v1, r3 = r2 + v2;
    if (base + 0 < N) { rowptr[base + 0] = r0; cnt[base + 0] = r0; }
    if (base + 1 < N) { rowptr[base + 1] = r1; cnt[base + 1] = r1; }
    if (base + 2 < N) { rowptr[base + 2] = r2; cnt[base + 2] = r2; }
    if (base + 3 < N) { rowptr[base + 3] = r3; cnt[base + 3] = r3; }
}

__global__ void k_fill(const int* __restrict__ src, const int* __restrict__ dst,
                       int* __restrict__ cursor, int* __restrict__ col, int E) {
    int e = blockIdx.x * 256 + threadIdx.x;
    if (e < E) {
        int p = atomicAdd(&cursor[dst[e]], 1);
        col[p] = src[e];
    }
}

__global__ void k_dinv(const int* __restrict__ rowptr, float* __restrict__ dinv, int N) {
    int v = blockIdx.x * 256 + threadIdx.x;
    if (v < N) {
        float deg = (float)(rowptr[v + 1] - rowptr[v]) + 1.0f;  // + self loop
        dinv[v] = 1.0f / sqrtf(deg);
    }
}

// pack h0 = [x | s] as bf16, row stride 128
__global__ void k_pack(const float4* __restrict__ xi, const float4* __restrict__ si,
                       ushort* __restrict__ h, int n4) {   // n4 = N*16
    int i = blockIdx.x * 256 + threadIdx.x;
    if (i >= n4) return;
    int row = i >> 4, c4 = i & 15;
    float4 xv = xi[i], sv = si[i];
    ushort4 xo, so;
    xo.x = f2bf(xv.x); xo.y = f2bf(xv.y); xo.z = f2bf(xv.z); xo.w = f2bf(xv.w);
    so.x = f2bf(sv.x); so.y = f2bf(sv.y); so.z = f2bf(sv.z); so.w = f2bf(sv.w);
    *reinterpret_cast<ushort4*>(&h[(size_t)row * 128 + c4 * 4]) = xo;
    *reinterpret_cast<ushort4*>(&h[(size_t)row * 128 + 64 + c4 * 4]) = so;
}

// weights: transpose + convert to bf16 once. WT[j][k] = W[k][j]
__global__ void k_prep(const float* __restrict__ W1, const float* __restrict__ W2,
                       const float* __restrict__ Wg, const float* __restrict__ Wh,
                       ushort* __restrict__ W1T, ushort* __restrict__ W2T,
                       ushort* __restrict__ WgT, ushort* __restrict__ WhT, int L) {
    int i = blockIdx.x * 256 + threadIdx.x;
    int n1 = L * 8192, n2 = L * 4096;
    if (i < n1) {
        int li = i >> 13, r = i & 8191, j = r >> 7, kk = r & 127;
        W1T[i] = f2bf(W1[(size_t)li * 8192 + kk * 64 + j]);
    } else if (i < n1 + n2) {
        int t = i - n1; int li = t >> 12, r = t & 4095, j = r >> 6, kk = r & 63;
        W2T[t] = f2bf(W2[(size_t)li * 4096 + kk * 64 + j]);
    } else if (i < n1 + 2 * n2) {
        int t = i - n1 - n2; int li = t >> 12, r = t & 4095, j = r >> 6, kk = r & 63;
        WgT[t] = f2bf(Wg[(size_t)li * 4096 + kk * 64 + j]);
    } else if (i < n1 + 2 * n2 + 8192) {
        int t = i - n1 - 2 * n2; int j = t >> 7, kk = t & 127;
        WhT[t] = f2bf(Wh[kk * 64 + j]);
    }
}

// ---------------- fused gather: GIN agg of h AND dinv-weighted agg of s ----------------
// one wave per dst row; lane l holds features (2l, 2l+1); f32 accum, bf16 out
__global__ __launch_bounds__(256)
void k_agg(const uint* __restrict__ h32, const float* __restrict__ dinv,
           const int* __restrict__ rowptr, const int* __restrict__ col,
           uint* __restrict__ g32, uint* __restrict__ tb32, int N) {
    int w = threadIdx.x >> 6, l = threadIdx.x & 63;
    int v = blockIdx.x * 4 + w;
    if (v >= N) return;
    float dv = dinv[v];
    float2 hv = bf2f2(h32[(size_t)v * 64 + l]);
    float ax = hv.x, ay = hv.y;
    float dx = dv * hv.x, dy = dv * hv.y;
    int k = rowptr[v], end = rowptr[v + 1];
    for (; k + 3 < end; k += 4) {
        int u0 = col[k], u1 = col[k + 1], u2 = col[k + 2], u3 = col[k + 3];
        float d0 = dinv[u0], d1 = dinv[u1], d2 = dinv[u2], d3 = dinv[u3];
        float2 a = bf2f2(h32[(size_t)u0 * 64 + l]);
        float2 b = bf2f2(h32[(size_t)u1 * 64 + l]);
        float2 c = bf2f2(h32[(size_t)u2 * 64 + l]);
        float2 e = bf2f2(h32[(size_t)u3 * 64 + l]);
        ax += (a.x + b.x) + (c.x + e.x);
        ay += (a.y + b.y) + (c.y + e.y);
        dx = fmaf(d0, a.x, fmaf(d1, b.x, fmaf(d2, c.x, fmaf(d3, e.x, dx))));
        dy = fmaf(d0, a.y, fmaf(d1, b.y, fmaf(d2, c.y, fmaf(d3, e.y, dy))));
    }
    for (; k < end; ++k) {
        int u = col[k];
        float du = dinv[u];
        float2 a = bf2f2(h32[(size_t)u * 64 + l]);
        ax += a.x; ay += a.y;
        dx = fmaf(du, a.x, dx);
        dy = fmaf(du, a.y, dy);
    }
    g32[(size_t)v * 64 + l] = packbf(ax, ay);
    if (l >= 32) tb32[(size_t)v * 32 + (l - 32)] = packbf(dv * dx, dv * dy);
}

// ---------------- MFMA layer: x' = leaky(g@W1)@W2 ; s' = tanh(tb@Wg + bg) ----------------
// 256 thr = 4 waves, each wave 16 rows; all operands bf16, f32 accum.
__global__ __launch_bounds__(256)
void k_layer_mfma(const ushort* __restrict__ g,   // [N][128] bf16
                  const ushort* __restrict__ tb,  // [N][64]  bf16
                  const ushort* __restrict__ W1T, // [64][128]
                  const ushort* __restrict__ W2T, // [64][64]
                  const ushort* __restrict__ WgT, // [64][64]
                  const float* __restrict__ bg,
                  ushort* __restrict__ hout, int N) {
    __shared__ short sT[4][1024];   // per-wave 16x64 bf16 T-tile, XOR-swizzled
    int w = threadIdx.x >> 6, l = threadIdx.x & 63;
    int p = l >> 4, q16 = l & 15;
    int r0 = blockIdx.x * 64 + w * 16;
    int arow = r0 + q16; if (arow >= N) arow = N - 1;   // clamp: no OOB reads
    f32x4 acc1[4] = {};
    // stage 1: T = g @ W1  (K=128)
#pragma unroll
    for (int kt = 0; kt < 4; ++kt) {
        bf16x8 a = *reinterpret_cast<const bf16x8*>(&g[(size_t)arow * 128 + kt * 32 + p * 8]);
#pragma unroll
        for (int jt = 0; jt < 4; ++jt) {
            bf16x8 b = *reinterpret_cast<const bf16x8*>(&W1T[(size_t)(jt * 16 + q16) * 128 + kt * 32 + p * 8]);
            acc1[jt] = __builtin_amdgcn_mfma_f32_16x16x32_bf16(a, b, acc1[jt], 0, 0, 0);
        }
    }
    // leaky + write T-tile to LDS (swizzle: short-index col ^ ((row&7)<<3))
#pragma unroll
    for (int jt = 0; jt < 4; ++jt) {
#pragma unroll
        for (int q = 0; q < 4; ++q) {
            float v = acc1[jt][q];
            v = v > 0.f ? v : 0.01f * v;
            int m = 4 * p + q;
            int c = jt * 16 + q16;
            sT[w][m * 64 + (c ^ ((m & 7) << 3))] = (short)f2bf(v);
        }
    }
    __syncthreads();
    // stage 2: x' = T @ W2 ; stage 3: s'pre = tb @ Wg   (K=64)
    f32x4 acc2[4] = {}, acc3[4] = {};
#pragma unroll
    for (int kt = 0; kt < 2; ++kt) {
        int koff = kt * 32 + p * 8;
        bf16x8 at = *reinterpret_cast<const bf16x8*>(&sT[w][q16 * 64 + (koff ^ ((q16 & 7) << 3))]);
        bf16x8 av = *reinterpret_cast<const bf16x8*>(&tb[(size_t)arow * 64 + koff]);
#pragma unroll
        for (int jt = 0; jt < 4; ++jt) {
            bf16x8 b2 = *reinterpret_cast<const bf16x8*>(&W2T[(size_t)(jt * 16 + q16) * 64 + koff]);
            bf16x8 b3 = *reinterpret_cast<const bf16x8*>(&WgT[(size_t)(jt * 16 + q16) * 64 + koff]);
            acc2[jt] = __builtin_amdgcn_mfma_f32_16x16x32_bf16(at, b2, acc2[jt], 0, 0, 0);
            acc3[jt] = __builtin_amdgcn_mfma_f32_16x16x32_bf16(av, b3, acc3[jt], 0, 0, 0);
        }
    }
    // epilogue: h' = [x' | tanh(s'pre + bg)]
#pragma unroll
    for (int jt = 0; jt < 4; ++jt) {
        int c = jt * 16 + q16;
        float bgv = bg[c];
#pragma unroll
        for (int q = 0; q < 4; ++q) {
            int row = r0 + 4 * p + q;
            if (row < N) {
                hout[(size_t)row * 128 + c] = f2bf(acc2[jt][q]);
                hout[(size_t)row * 128 + 64 + c] = f2bf(tanhf(acc3[jt][q] + bgv));
            }
        }
    }
}

// ---------------- final MFMA GEMM: out = h @ Wh + bh (f32 out) ----------------
__global__ __launch_bounds__(256)
void k_final_mfma(const ushort* __restrict__ h, const ushort* __restrict__ WhT,
                  const float* __restrict__ bh, float* __restrict__ out, int N) {
    int w = threadIdx.x >> 6, l = threadIdx.x & 63;
    int p = l >> 4, q16 = l & 15;
    int r0 = blockIdx.x * 64 + w * 16;
    int arow = r0 + q16; if (arow >= N) arow = N - 1;
    f32x4 acc[4] = {};
#pragma unroll
    for (int kt = 0; kt < 4; ++kt) {
        bf16x8 a = *reinterpret_cast<const bf16x8*>(&h[(size_t)arow * 128 + kt * 32 + p * 8]);
#pragma unroll
        for (int jt = 0; jt < 4; ++jt) {
            bf16x8 b = *reinterpret_cast<const bf16x8*>(&WhT[(size_t)(jt * 16 + q16) * 128 + kt * 32 + p * 8]);
            acc[jt] = __builtin_amdgcn_mfma_f32_16x16x32_bf16(a, b, acc[jt], 0, 0, 0);
        }
    }
#pragma unroll
    for (int jt = 0; jt < 4; ++jt) {
        int c = jt * 16 + q16;
        float bias = bh[c];
#pragma unroll
        for (int q = 0; q < 4; ++q) {
            int row = r0 + 4 * p + q;
            if (row < N) out[(size_t)row * 64 + c] = acc[jt][q] + bias;
        }
    }
}

// ---------------- BatchNorm (final layer only) ----------------
__global__ __launch_bounds__(256)
void k_bnstats(const ushort* __restrict__ h, float* __restrict__ stats, int N) {
    __shared__ float ls[4][64], ls2[4][64];
    int w = threadIdx.x >> 6, j = threadIdx.x & 63;
    float s = 0.f, s2 = 0.f;
    for (int r = blockIdx.x * 4 + w; r < N; r += gridDim.x * 4) {
        float v = __uint_as_float((uint)h[(size_t)r * 128 + j] << 16);
        s += v; s2 += v * v;
    }
    ls[w][j] = s; ls2[w][j] = s2;
    __syncthreads();
    if (w == 0) {
        s = ls[0][j] + ls[1][j] + ls[2][j] + ls[3][j];
        s2 = ls2[0][j] + ls2[1][j] + ls2[2][j] + ls2[3][j];
        atomicAdd(&stats[j], s);
        atomicAdd(&stats[64 + j], s2);
    }
}

__global__ void k_bnapply(ushort* __restrict__ h, const float* __restrict__ stats,
                          const float* __restrict__ gamma, const float* __restrict__ beta,
                          float* __restrict__ xlocal, int N) {
    int i = blockIdx.x * 256 + threadIdx.x;
    if (i < N * 64) {
        int r = i >> 6, j = i & 63;
        float invN = 1.0f / (float)N;
        float mean = stats[j] * invN;
        float var = stats[64 + j] * invN - mean * mean;
        float inv = rsqrtf(var + 1e-4f);
        float v = __uint_as_float((uint)h[(size_t)r * 128 + j] << 16);
        float xn = gamma[j] * (v - mean) * inv + beta[j];
        xlocal[i] = xn;
        h[(size_t)r * 128 + j] = f2bf(xn);
    }
}

// ---------------- pooling: one block per graph (batch is sorted) ----------------
__global__ __launch_bounds__(256)
void k_pool(const float* __restrict__ out, const int* __restrict__ batch,
            float* __restrict__ pooled, int N) {
    int g = blockIdx.x;
    int lo, hi;
    { int a = 0, b = N; while (a < b) { int m = (a + b) >> 1; if (batch[m] < g) a = m + 1; else b = m; } lo = a; }
    { int a = lo, b = N; while (a < b) { int m = (a + b) >> 1; if (batch[m] < g + 1) a = m + 1; else b = m; } hi = a; }
    int w = threadIdx.x >> 6, j = threadIdx.x & 63;
    float s = 0.f;
    for (int r = lo + w; r < hi; r += 4) s += out[(size_t)r * 64 + j];
    __shared__ float ls[4][64];
    ls[w][j] = s;
    __syncthreads();
    if (w == 0) pooled[g * 64 + j] = ls[0][j] + ls[1][j] + ls[2][j] + ls[3][j];
}

extern "C" void kernel_launch(void* const* d_in, const int* in_sizes, int n_in,
                              void* d_out, int out_size, void* d_ws, size_t ws_size,
                              hipStream_t stream) {
    const float* x_in  = (const float*)d_in[0];
    const float* s_in  = (const float*)d_in[1];
    const float* W1    = (const float*)d_in[2];
    const float* W2    = (const float*)d_in[3];
    const float* gamma = (const float*)d_in[4];
    const float* beta  = (const float*)d_in[5];
    const float* Wg    = (const float*)d_in[6];
    const float* bg    = (const float*)d_in[7];
    const float* Wh    = (const float*)d_in[8];
    const float* bh    = (const float*)d_in[9];
    const int*   ei    = (const int*)d_in[10];
    const int*   batch = (const int*)d_in[11];

    int N = in_sizes[0] / 64;
    int E = in_sizes[10] / 2;
    int L = in_sizes[2] / 8192;
    int G = out_size / 64 - N;

    const int* src = ei;
    const int* dst = ei + E;

    float* pooled = (float*)d_out;
    float* xlocal = pooled + (size_t)G * 64;      // final BN'd x (f32) lands here
    ushort* tb16  = (ushort*)xlocal;              // tb (bf16 N*64) borrows this slot during layers

    char* p = (char*)d_ws;
    auto alloc = [&](size_t bytes) { char* r = p; p += (bytes + 255) & ~(size_t)255; return r; };
    ushort* h16  = (ushort*)alloc((size_t)N * 128 * 2);
    ushort* g16  = (ushort*)alloc((size_t)N * 128 * 2);
    float* dinv  = (float*)alloc((size_t)N * 4);
    float* stats = (float*)alloc(128 * 4);
    int* rowptr  = (int*)alloc((size_t)(N + 1) * 4);
    int* cnt     = (int*)alloc((size_t)N * 4);
    int* col     = (int*)alloc((size_t)E * 4);
    int* btot    = (int*)alloc(256 * 4);
    int* boff    = (int*)alloc(256 * 4);
    ushort* W1T  = (ushort*)alloc((size_t)L * 8192 * 2);
    ushort* W2T  = (ushort*)alloc((size_t)L * 4096 * 2);
    ushort* WgT  = (ushort*)alloc((size_t)L * 4096 * 2);
    ushort* WhT  = (ushort*)alloc(8192 * 2);
    const uint* h32 = (const uint*)h16;
    uint* g32 = (uint*)g16;
    uint* tb32 = (uint*)tb16;
    float* fout = (float*)g16;   // final f32 out reuses g slot (N*64*4 == N*128*2)

    int NB = (N + 1023) / 1024;
    int nprep = L * 16384 + 8192;

    hipMemsetAsync(cnt, 0, (size_t)N * sizeof(int), stream);
    k_prep<<<(nprep + 255) / 256, 256, 0, stream>>>(W1, W2, Wg, Wh, W1T, W2T, WgT, WhT, L);
    k_hist<<<(E + 255) / 256, 256, 0, stream>>>(dst, cnt, E);
    k_scanA<<<NB, 256, 0, stream>>>(cnt, btot, N);
    k_scanB<<<1, 256, 0, stream>>>(btot, boff, rowptr, NB, N, E);
    k_scanC<<<NB, 256, 0, stream>>>(cnt, boff, rowptr, N);
    k_fill<<<(E + 255) / 256, 256, 0, stream>>>(src, dst, cnt, col, E);
    k_dinv<<<(N + 255) / 256, 256, 0, stream>>>(rowptr, dinv, N);
    k_pack<<<(N * 16 + 255) / 256, 256, 0, stream>>>((const float4*)x_in, (const float4*)s_in, h16, N * 16);

    int gBlk = (N + 63) / 64;
    for (int i = 0; i < L; ++i) {
        k_agg<<<(N + 3) / 4, 256, 0, stream>>>(h32, dinv, rowptr, col, g32, tb32, N);
        k_layer_mfma<<<gBlk, 256, 0, stream>>>(g16, tb16,
                                               W1T + (size_t)i * 8192, W2T + (size_t)i * 4096,
                                               WgT + (size_t)i * 4096, bg + (size_t)i * 64,
                                               h16, N);
    }

    hipMemsetAsync(stats, 0, 128 * sizeof(float), stream);
    k_bnstats<<<256, 256, 0, stream>>>(h16, stats, N);
    k_bnapply<<<(N * 64 + 255) / 256, 256, 0, stream>>>(h16, stats,
                                                        gamma + (size_t)(L - 1) * 64,
                                                        beta + (size_t)(L - 1) * 64,
                                                        xlocal, N);
    k_final_mfma<<<gBlk, 256, 0, stream>>>(h16, WhT, bh, fout, N);
    k_pool<<<G, 256, 0, stream>>>(fout, batch, pooled, N);
}

// Round 4
// 354.955 us; speedup vs baseline: 3.8967x; 1.1303x over previous
//
#include <hip/hip_runtime.h>
#include <hip/hip_bf16.h>

typedef unsigned int uint;
typedef unsigned short ushort;
typedef __attribute__((ext_vector_type(8))) short bf16x8;
typedef __attribute__((ext_vector_type(4))) float f32x4;

// ---- bf16 helpers (f32 accumulate everywhere; bf16 only for stored tensors) ----
__device__ __forceinline__ float2 bf2f2(uint p) {
    float2 r;
    r.x = __uint_as_float(p << 16);
    r.y = __uint_as_float(p & 0xffff0000u);
    return r;
}
__device__ __forceinline__ ushort f2bf(float f) {
    uint u = __float_as_uint(f);
    return (ushort)((u + 0x7fffu + ((u >> 16) & 1u)) >> 16);
}
__device__ __forceinline__ uint packbf(float a, float b) {
    return (uint)f2bf(a) | ((uint)f2bf(b) << 16);
}

// ---------------- CSR build ----------------
__global__ void k_hist(const int* __restrict__ dst, int* __restrict__ cnt, int E) {
    int e = (blockIdx.x * 256 + threadIdx.x) * 4;
    if (e + 3 < E) {
        int4 d = *reinterpret_cast<const int4*>(&dst[e]);
        atomicAdd(&cnt[d.x], 1);
        atomicAdd(&cnt[d.y], 1);
        atomicAdd(&cnt[d.z], 1);
        atomicAdd(&cnt[d.w], 1);
    } else {
        for (int q = 0; q < 4; ++q)
            if (e + q < E) atomicAdd(&cnt[dst[e + q]], 1);
    }
}

__device__ __forceinline__ int block_excl_scan(int tsum, int tid, int* wtot) {
    int lane = tid & 63, w = tid >> 6;
    int incl = tsum;
    for (int off = 1; off < 64; off <<= 1) {
        int t = __shfl_up(incl, off);
        if (lane >= off) incl += t;
    }
    if (lane == 63) wtot[w] = incl;
    __syncthreads();
    int woff = 0;
    if (w > 0) woff = wtot[0];
    if (w > 1) woff += wtot[1];
    if (w > 2) woff += wtot[2];
    return woff + incl - tsum;
}

__global__ __launch_bounds__(256)
void k_scanA(const int* __restrict__ cnt, int* __restrict__ btot, int N) {
    __shared__ int wtot[4];
    int tid = threadIdx.x;
    int base = blockIdx.x * 1024 + tid * 4;
    int s = 0;
    if (base + 3 < N) {
        int4 v = *reinterpret_cast<const int4*>(&cnt[base]);
        s = v.x + v.y + v.z + v.w;
    } else {
#pragma unroll
        for (int q = 0; q < 4; ++q) { int i = base + q; if (i < N) s += cnt[i]; }
    }
    int lane = tid & 63, w = tid >> 6;
    for (int off = 32; off; off >>= 1) s += __shfl_down(s, off);
    if (lane == 0) wtot[w] = s;
    __syncthreads();
    if (tid == 0) btot[blockIdx.x] = wtot[0] + wtot[1] + wtot[2] + wtot[3];
}

__global__ __launch_bounds__(256)
void k_scanB(const int* __restrict__ btot, int* __restrict__ boff,
             int* __restrict__ rowptr, int NB, int N, int E) {
    __shared__ int wtot[4];
    int tid = threadIdx.x;
    int v = (tid < NB) ? btot[tid] : 0;
    int ex = block_excl_scan(v, tid, wtot);
    if (tid < NB) boff[tid] = ex;
    if (tid == 0) rowptr[N] = E;
}

// re-scan chunks + write rowptr/cursor; fused dinv (pre-scan cnt values ARE degrees)
__global__ __launch_bounds__(256)
void k_scanC(int* __restrict__ cnt, const int* __restrict__ boff,
             int* __restrict__ rowptr, float* __restrict__ dinv, int N) {
    __shared__ int wtot[4];
    int tid = threadIdx.x;
    int base = blockIdx.x * 1024 + tid * 4;
    int v0 = 0, v1 = 0, v2 = 0, v3 = 0;
    if (base + 3 < N) {
        int4 v = *reinterpret_cast<const int4*>(&cnt[base]);
        v0 = v.x; v1 = v.y; v2 = v.z; v3 = v.w;
    } else {
        if (base + 0 < N) v0 = cnt[base + 0];
        if (base + 1 < N) v1 = cnt[base + 1];
        if (base + 2 < N) v2 = cnt[base + 2];
        if (base + 3 < N) v3 = cnt[base + 3];
    }
    int tsum = v0 + v1 + v2 + v3;
    int ex = block_excl_scan(tsum, tid, wtot) + boff[blockIdx.x];
    int r0 = ex, r1 = ex + v0, r2 = r1 + v1, r3 = r2 + v2;
    if (base + 0 < N) { rowptr[base + 0] = r0; cnt[base + 0] = r0; dinv[base + 0] = rsqrtf((float)v0 + 1.0f); }
    if (base + 1 < N) { rowptr[base + 1] = r1; cnt[base + 1] = r1; dinv[base + 1] = rsqrtf((float)v1 + 1.0f); }
    if (base + 2 < N) { rowptr[base + 2] = r2; cnt[base + 2] = r2; dinv[base + 2] = rsqrtf((float)v2 + 1.0f); }
    if (base + 3 < N) { rowptr[base + 3] = r3; cnt[base + 3] = r3; dinv[base + 3] = rsqrtf((float)v3 + 1.0f); }
}

__global__ void k_fill(const int* __restrict__ src, const int* __restrict__ dst,
                       int* __restrict__ cursor, int* __restrict__ col, int E) {
    int e = (blockIdx.x * 256 + threadIdx.x) * 4;
    if (e + 3 < E) {
        int4 s = *reinterpret_cast<const int4*>(&src[e]);
        int4 d = *reinterpret_cast<const int4*>(&dst[e]);
        col[atomicAdd(&cursor[d.x], 1)] = s.x;
        col[atomicAdd(&cursor[d.y], 1)] = s.y;
        col[atomicAdd(&cursor[d.z], 1)] = s.z;
        col[atomicAdd(&cursor[d.w], 1)] = s.w;
    } else {
        for (int q = 0; q < 4; ++q)
            if (e + q < E) col[atomicAdd(&cursor[dst[e + q]], 1)] = src[e + q];
    }
}

// pack h0 = [x | s] as bf16, row stride 128
__global__ void k_pack(const float4* __restrict__ xi, const float4* __restrict__ si,
                       ushort* __restrict__ h, int n4) {   // n4 = N*16
    int i = blockIdx.x * 256 + threadIdx.x;
    if (i >= n4) return;
    int row = i >> 4, c4 = i & 15;
    float4 xv = xi[i], sv = si[i];
    ushort4 xo, so;
    xo.x = f2bf(xv.x); xo.y = f2bf(xv.y); xo.z = f2bf(xv.z); xo.w = f2bf(xv.w);
    so.x = f2bf(sv.x); so.y = f2bf(sv.y); so.z = f2bf(sv.z); so.w = f2bf(sv.w);
    *reinterpret_cast<ushort4*>(&h[(size_t)row * 128 + c4 * 4]) = xo;
    *reinterpret_cast<ushort4*>(&h[(size_t)row * 128 + 64 + c4 * 4]) = so;
}

// weights: transpose + convert to bf16 once. WT[j][k] = W[k][j]  (Wh stays f32, used by k_out)
__global__ void k_prep(const float* __restrict__ W1, const float* __restrict__ W2,
                       const float* __restrict__ Wg,
                       ushort* __restrict__ W1T, ushort* __restrict__ W2T,
                       ushort* __restrict__ WgT, int L) {
    int i = blockIdx.x * 256 + threadIdx.x;
    int n1 = L * 8192, n2 = L * 4096;
    if (i < n1) {
        int li = i >> 13, r = i & 8191, j = r >> 7, kk = r & 127;
        W1T[i] = f2bf(W1[(size_t)li * 8192 + kk * 64 + j]);
    } else if (i < n1 + n2) {
        int t = i - n1; int li = t >> 12, r = t & 4095, j = r >> 6, kk = r & 63;
        W2T[t] = f2bf(W2[(size_t)li * 4096 + kk * 64 + j]);
    } else if (i < n1 + 2 * n2) {
        int t = i - n1 - n2; int li = t >> 12, r = t & 4095, j = r >> 6, kk = r & 63;
        WgT[t] = f2bf(Wg[(size_t)li * 4096 + kk * 64 + j]);
    }
}

// ---------------- fused gather: GIN agg of h AND dinv-weighted agg of s ----------------
// one wave per dst row; lane l holds features (2l, 2l+1); f32 accum, bf16 out
// col-index loads software-pipelined one group ahead to break the idx->gather chain
__global__ __launch_bounds__(256)
void k_agg(const uint* __restrict__ h32, const float* __restrict__ dinv,
           const int* __restrict__ rowptr, const int* __restrict__ col,
           uint* __restrict__ g32, uint* __restrict__ tb32, int N) {
    int w = threadIdx.x >> 6, l = threadIdx.x & 63;
    int v = blockIdx.x * 4 + w;
    if (v >= N) return;
    float dv = dinv[v];
    float2 hv = bf2f2(h32[(size_t)v * 64 + l]);
    float ax = hv.x, ay = hv.y;
    float dx = dv * hv.x, dy = dv * hv.y;
    int k = rowptr[v], end = rowptr[v + 1];
    int u0 = 0, u1 = 0, u2 = 0, u3 = 0;
    if (k + 3 < end) { u0 = col[k]; u1 = col[k + 1]; u2 = col[k + 2]; u3 = col[k + 3]; }
    for (; k + 7 < end; k += 4) {
        int n0 = col[k + 4], n1 = col[k + 5], n2 = col[k + 6], n3 = col[k + 7];
        float d0 = dinv[u0], d1 = dinv[u1], d2 = dinv[u2], d3 = dinv[u3];
        float2 a = bf2f2(h32[(size_t)u0 * 64 + l]);
        float2 b = bf2f2(h32[(size_t)u1 * 64 + l]);
        float2 c = bf2f2(h32[(size_t)u2 * 64 + l]);
        float2 e = bf2f2(h32[(size_t)u3 * 64 + l]);
        ax += (a.x + b.x) + (c.x + e.x);
        ay += (a.y + b.y) + (c.y + e.y);
        dx = fmaf(d0, a.x, fmaf(d1, b.x, fmaf(d2, c.x, fmaf(d3, e.x, dx))));
        dy = fmaf(d0, a.y, fmaf(d1, b.y, fmaf(d2, c.y, fmaf(d3, e.y, dy))));
        u0 = n0; u1 = n1; u2 = n2; u3 = n3;
    }
    if (k + 3 < end) {
        float d0 = dinv[u0], d1 = dinv[u1], d2 = dinv[u2], d3 = dinv[u3];
        float2 a = bf2f2(h32[(size_t)u0 * 64 + l]);
        float2 b = bf2f2(h32[(size_t)u1 * 64 + l]);
        float2 c = bf2f2(h32[(size_t)u2 * 64 + l]);
        float2 e = bf2f2(h32[(size_t)u3 * 64 + l]);
        ax += (a.x + b.x) + (c.x + e.x);
        ay += (a.y + b.y) + (c.y + e.y);
        dx = fmaf(d0, a.x, fmaf(d1, b.x, fmaf(d2, c.x, fmaf(d3, e.x, dx))));
        dy = fmaf(d0, a.y, fmaf(d1, b.y, fmaf(d2, c.y, fmaf(d3, e.y, dy))));
        k += 4;
    }
    for (; k < end; ++k) {
        int u = col[k];
        float du = dinv[u];
        float2 a = bf2f2(h32[(size_t)u * 64 + l]);
        ax += a.x; ay += a.y;
        dx = fmaf(du, a.x, dx);
        dy = fmaf(du, a.y, dy);
    }
    g32[(size_t)v * 64 + l] = packbf(ax, ay);
    if (l >= 32) tb32[(size_t)v * 32 + (l - 32)] = packbf(dv * dx, dv * dy);
}

// ---------------- MFMA layer: x' = leaky(g@W1)@W2 ; s' = tanh(tb@Wg + bg) ----------------
__global__ __launch_bounds__(256)
void k_layer_mfma(const ushort* __restrict__ g,   // [N][128] bf16
                  const ushort* __restrict__ tb,  // [N][64]  bf16
                  const ushort* __restrict__ W1T, // [64][128]
                  const ushort* __restrict__ W2T, // [64][64]
                  const ushort* __restrict__ WgT, // [64][64]
                  const float* __restrict__ bg,
                  ushort* __restrict__ hout, int N) {
    __shared__ short sT[4][1024];   // per-wave 16x64 bf16 T-tile, XOR-swizzled
    int w = threadIdx.x >> 6, l = threadIdx.x & 63;
    int p = l >> 4, q16 = l & 15;
    int r0 = blockIdx.x * 64 + w * 16;
    int arow = r0 + q16; if (arow >= N) arow = N - 1;   // clamp: no OOB reads
    f32x4 acc1[4] = {};
#pragma unroll
    for (int kt = 0; kt < 4; ++kt) {
        bf16x8 a = *reinterpret_cast<const bf16x8*>(&g[(size_t)arow * 128 + kt * 32 + p * 8]);
#pragma unroll
        for (int jt = 0; jt < 4; ++jt) {
            bf16x8 b = *reinterpret_cast<const bf16x8*>(&W1T[(size_t)(jt * 16 + q16) * 128 + kt * 32 + p * 8]);
            acc1[jt] = __builtin_amdgcn_mfma_f32_16x16x32_bf16(a, b, acc1[jt], 0, 0, 0);
        }
    }
#pragma unroll
    for (int jt = 0; jt < 4; ++jt) {
#pragma unroll
        for (int q = 0; q < 4; ++q) {
            float v = acc1[jt][q];
            v = v > 0.f ? v : 0.01f * v;
            int m = 4 * p + q;
            int c = jt * 16 + q16;
            sT[w][m * 64 + (c ^ ((m & 7) << 3))] = (short)f2bf(v);
        }
    }
    __syncthreads();
    f32x4 acc2[4] = {}, acc3[4] = {};
#pragma unroll
    for (int kt = 0; kt < 2; ++kt) {
        int koff = kt * 32 + p * 8;
        bf16x8 at = *reinterpret_cast<const bf16x8*>(&sT[w][q16 * 64 + (koff ^ ((q16 & 7) << 3))]);
        bf16x8 av = *reinterpret_cast<const bf16x8*>(&tb[(size_t)arow * 64 + koff]);
#pragma unroll
        for (int jt = 0; jt < 4; ++jt) {
            bf16x8 b2 = *reinterpret_cast<const bf16x8*>(&W2T[(size_t)(jt * 16 + q16) * 64 + koff]);
            bf16x8 b3 = *reinterpret_cast<const bf16x8*>(&WgT[(size_t)(jt * 16 + q16) * 64 + koff]);
            acc2[jt] = __builtin_amdgcn_mfma_f32_16x16x32_bf16(at, b2, acc2[jt], 0, 0, 0);
            acc3[jt] = __builtin_amdgcn_mfma_f32_16x16x32_bf16(av, b3, acc3[jt], 0, 0, 0);
        }
    }
#pragma unroll
    for (int jt = 0; jt < 4; ++jt) {
        int c = jt * 16 + q16;
        float bgv = bg[c];
#pragma unroll
        for (int q = 0; q < 4; ++q) {
            int row = r0 + 4 * p + q;
            if (row < N) {
                hout[(size_t)row * 128 + c] = f2bf(acc2[jt][q]);
                hout[(size_t)row * 128 + 64 + c] = f2bf(tanhf(acc3[jt][q] + bgv));
            }
        }
    }
}

// ---------------- BatchNorm stats (final layer only) ----------------
__global__ __launch_bounds__(256)
void k_bnstats(const ushort* __restrict__ h, float* __restrict__ stats, int N) {
    __shared__ float ls[4][64], ls2[4][64];
    int w = threadIdx.x >> 6, j = threadIdx.x & 63;
    float s = 0.f, s2 = 0.f;
    for (int r = blockIdx.x * 4 + w; r < N; r += gridDim.x * 4) {
        float v = __uint_as_float((uint)h[(size_t)r * 128 + j] << 16);
        s += v; s2 += v * v;
    }
    ls[w][j] = s; ls2[w][j] = s2;
    __syncthreads();
    if (w == 0) {
        s = ls[0][j] + ls[1][j] + ls[2][j] + ls[3][j];
        s2 = ls2[0][j] + ls2[1][j] + ls2[2][j] + ls2[3][j];
        atomicAdd(&stats[j], s);
        atomicAdd(&stats[64 + j], s2);
    }
}

// ---------------- fused BN-apply + x_local write + per-graph pooled partials ----------------
// one wave per contiguous row chunk; lane l covers features (2l, 2l+1)
__global__ __launch_bounds__(256)
void k_bnpool(const uint* __restrict__ h32, const float* __restrict__ stats,
              const float* __restrict__ gamma, const float* __restrict__ beta,
              const int* __restrict__ batch, float* __restrict__ xlocal,
              float* __restrict__ ph, int* __restrict__ pcnt, int N, int rpw) {
    int wg = blockIdx.x * 4 + (threadIdx.x >> 6);
    int l = threadIdx.x & 63;
    int r = wg * rpw;
    int rend = r + rpw; if (rend > N) rend = N;
    if (r >= rend) return;
    float invN = 1.0f / (float)N;
    bool isx = (l < 32);
    int f0 = 2 * l, f1 = 2 * l + 1;
    float mean0 = 0.f, mean1 = 0.f, inv0 = 1.f, inv1 = 1.f;
    float ga0 = 0.f, ga1 = 0.f, be0 = 0.f, be1 = 0.f;
    if (isx) {
        mean0 = stats[f0] * invN; mean1 = stats[f1] * invN;
        float v0 = stats[64 + f0] * invN - mean0 * mean0;
        float v1 = stats[64 + f1] * invN - mean1 * mean1;
        inv0 = rsqrtf(v0 + 1e-4f); inv1 = rsqrtf(v1 + 1e-4f);
        ga0 = gamma[f0]; ga1 = gamma[f1]; be0 = beta[f0]; be1 = beta[f1];
    }
    int cur = batch[r];
    float a0 = 0.f, a1 = 0.f; int cnt = 0;
    for (; r < rend; ++r) {
        int b = batch[r];
        if (b != cur) {
            atomicAdd(&ph[cur * 128 + f0], a0);
            atomicAdd(&ph[cur * 128 + f1], a1);
            if (l == 0) atomicAdd(&pcnt[cur], cnt);
            a0 = 0.f; a1 = 0.f; cnt = 0; cur = b;
        }
        float2 f = bf2f2(h32[(size_t)r * 64 + l]);
        if (isx) {
            float xn0 = fmaf((f.x - mean0) * inv0, ga0, be0);
            float xn1 = fmaf((f.y - mean1) * inv1, ga1, be1);
            *reinterpret_cast<float2*>(&xlocal[(size_t)r * 64 + f0]) = make_float2(xn0, xn1);
            a0 += xn0; a1 += xn1;
        } else {
            a0 += f.x; a1 += f.y;
        }
        cnt++;
    }
    atomicAdd(&ph[cur * 128 + f0], a0);
    atomicAdd(&ph[cur * 128 + f1], a1);
    if (l == 0) atomicAdd(&pcnt[cur], cnt);
}

// ---------------- tiny final GEMM on pooled sums: pooled = ph @ Wh + n_g*bh  (all f32) ----------------
__global__ __launch_bounds__(256)
void k_out(const float* __restrict__ ph, const int* __restrict__ pcnt,
           const float* __restrict__ Wh, const float* __restrict__ bh,
           float* __restrict__ pooled, int G) {
    int t = blockIdx.x * 256 + threadIdx.x;
    if (t >= G * 64) return;
    int g = t >> 6, j = t & 63;
    float acc = bh[j] * (float)pcnt[g];
    const float* row = ph + g * 128;
#pragma unroll 4
    for (int k = 0; k < 128; ++k) acc = fmaf(row[k], Wh[k * 64 + j], acc);
    pooled[t] = acc;
}

extern "C" void kernel_launch(void* const* d_in, const int* in_sizes, int n_in,
                              void* d_out, int out_size, void* d_ws, size_t ws_size,
                              hipStream_t stream) {
    const float* x_in  = (const float*)d_in[0];
    const float* s_in  = (const float*)d_in[1];
    const float* W1    = (const float*)d_in[2];
    const float* W2    = (const float*)d_in[3];
    const float* gamma = (const float*)d_in[4];
    const float* beta  = (const float*)d_in[5];
    const float* Wg    = (const float*)d_in[6];
    const float* bg    = (const float*)d_in[7];
    const float* Wh    = (const float*)d_in[8];
    const float* bh    = (const float*)d_in[9];
    const int*   ei    = (const int*)d_in[10];
    const int*   batch = (const int*)d_in[11];

    int N = in_sizes[0] / 64;
    int E = in_sizes[10] / 2;
    int L = in_sizes[2] / 8192;
    int G = out_size / 64 - N;

    const int* src = ei;
    const int* dst = ei + E;

    float* pooled = (float*)d_out;
    float* xlocal = pooled + (size_t)G * 64;      // final BN'd x (f32) output
    ushort* tb16  = (ushort*)xlocal;              // tb (bf16 N*64) borrows this slot during layers

    char* p = (char*)d_ws;
    auto alloc = [&](size_t bytes) { char* r = p; p += (bytes + 255) & ~(size_t)255; return r; };
    ushort* h16  = (ushort*)alloc((size_t)N * 128 * 2);
    ushort* g16  = (ushort*)alloc((size_t)N * 128 * 2);
    float* dinv  = (float*)alloc((size_t)N * 4);
    float* stats = (float*)alloc(128 * 4);
    float* ph    = (float*)alloc((size_t)G * 128 * 4);   // pooled concat partials
    int* pcnt    = (int*)alloc((size_t)G * 4);           // per-graph row counts
    int* rowptr  = (int*)alloc((size_t)(N + 1) * 4);
    int* cnt     = (int*)alloc((size_t)N * 4);
    int* col     = (int*)alloc((size_t)E * 4);
    int* btot    = (int*)alloc(256 * 4);
    int* boff    = (int*)alloc(256 * 4);
    ushort* W1T  = (ushort*)alloc((size_t)L * 8192 * 2);
    ushort* W2T  = (ushort*)alloc((size_t)L * 4096 * 2);
    ushort* WgT  = (ushort*)alloc((size_t)L * 4096 * 2);
    const uint* h32 = (const uint*)h16;
    uint* g32 = (uint*)g16;
    uint* tb32 = (uint*)tb16;

    int NB = (N + 1023) / 1024;
    int nprep = L * 16384;
    int E4 = (E + 3) / 4;

    hipMemsetAsync(cnt, 0, (size_t)N * sizeof(int), stream);
    hipMemsetAsync(ph, 0, (size_t)G * 128 * sizeof(float), stream);
    hipMemsetAsync(pcnt, 0, (size_t)G * sizeof(int), stream);
    hipMemsetAsync(stats, 0, 128 * sizeof(float), stream);
    k_prep<<<(nprep + 255) / 256, 256, 0, stream>>>(W1, W2, Wg, W1T, W2T, WgT, L);
    k_hist<<<(E4 + 255) / 256, 256, 0, stream>>>(dst, cnt, E);
    k_scanA<<<NB, 256, 0, stream>>>(cnt, btot, N);
    k_scanB<<<1, 256, 0, stream>>>(btot, boff, rowptr, NB, N, E);
    k_scanC<<<NB, 256, 0, stream>>>(cnt, boff, rowptr, dinv, N);
    k_fill<<<(E4 + 255) / 256, 256, 0, stream>>>(src, dst, cnt, col, E);
    k_pack<<<(N * 16 + 255) / 256, 256, 0, stream>>>((const float4*)x_in, (const float4*)s_in, h16, N * 16);

    int gBlk = (N + 63) / 64;
    for (int i = 0; i < L; ++i) {
        k_agg<<<(N + 3) / 4, 256, 0, stream>>>(h32, dinv, rowptr, col, g32, tb32, N);
        k_layer_mfma<<<gBlk, 256, 0, stream>>>(g16, tb16,
                                               W1T + (size_t)i * 8192, W2T + (size_t)i * 4096,
                                               WgT + (size_t)i * 4096, bg + (size_t)i * 64,
                                               h16, N);
    }

    k_bnstats<<<256, 256, 0, stream>>>(h16, stats, N);
    int nwaves = 2048;
    int rpw = (N + nwaves - 1) / nwaves;
    k_bnpool<<<nwaves / 4, 256, 0, stream>>>(h32, stats,
                                             gamma + (size_t)(L - 1) * 64,
                                             beta + (size_t)(L - 1) * 64,
                                             batch, xlocal, ph, pcnt, N, rpw);
    k_out<<<(G * 64 + 255) / 256, 256, 0, stream>>>(ph, pcnt, Wh, bh, pooled, G);
}